// Round 2
// baseline (559.595 us; speedup 1.0000x reference)
//
#include <hip/hip_runtime.h>
#include <hip/hip_bf16.h>

#define B_  4
#define S_  2048
#define D_  640
#define H_  10
#define KD_ 64
// M = B_*S_ = 8192; QKV fused N = 3*H_*KD_ = 1920; K = 640

typedef __attribute__((ext_vector_type(8))) short  short8;
typedef __attribute__((ext_vector_type(4))) short  short4v;
typedef __attribute__((ext_vector_type(4))) float  floatx4;

static __device__ __forceinline__ short f2bf(float f) {
    union { __hip_bfloat16 h; short s; } u;
    u.h = __float2bfloat16(f);
    return u.s;
}

// ---------------------------------------------------------------------------
// Kernel 0: downcast x (fp32) -> xb (bf16). 4 elems/thread.
// ---------------------------------------------------------------------------
__global__ __launch_bounds__(256) void pack_x(
        const float* __restrict__ x, short* __restrict__ xb) {
    int idx = (blockIdx.x * 256 + threadIdx.x) * 4;
    float4 v = *(const float4*)(x + idx);
    short4v o;
    o[0] = f2bf(v.x); o[1] = f2bf(v.y); o[2] = f2bf(v.z); o[3] = f2bf(v.w);
    *(short4v*)(xb + idx) = o;
}

// ---------------------------------------------------------------------------
// Kernel 1: weight transposes (fp32 in, bf16 out).
// BigT[n][d], n = w*640 + h*64 + kd  (w: 0=q,1=k,2=v), BigT[n][d] = W_w[h][d][kd]
// WoT[n][f] = Wo[f][n]
// ---------------------------------------------------------------------------
__global__ __launch_bounds__(256) void transpose_weights(
        const float* __restrict__ Wq, const float* __restrict__ Wk,
        const float* __restrict__ Wv, const float* __restrict__ Wo,
        short* __restrict__ BigT, short* __restrict__ WoT) {
    int idx = blockIdx.x * 256 + threadIdx.x;
    const int total1 = 1920 * 640;
    const int total2 = 640 * 640;
    if (idx < total1) {
        int n = idx / 640, d = idx % 640;
        int w = n / 640, r = n % 640;
        int h = r / 64, kd = r % 64;
        const float* W = (w == 0) ? Wq : (w == 1) ? Wk : Wv;
        BigT[n * 640 + d] = f2bf(W[(h * 640 + d) * 64 + kd]);
    } else if (idx < total1 + total2) {
        int i2 = idx - total1;
        int n = i2 / 640, f = i2 % 640;
        WoT[n * 640 + f] = f2bf(Wo[f * 640 + n]);
    }
}

// ---------------------------------------------------------------------------
// Kernel 2: fused QKV projection GEMM.  Y(8192x1920) = X(8192x640) @ BigT^T.
// Block = 256 threads (4 waves). Tile 128(M) x 64(N). Each wave: 32x64 via
// 2x4 accumulators of 16x16, K-step 32 (mfma_f32_16x16x32_bf16).
// Epilogue: w==0 -> q (scaled by 1/8*log2e), w==1 -> k, w==2 -> v transposed.
// ---------------------------------------------------------------------------
__global__ __launch_bounds__(256) void qkv_gemm(
        const short* __restrict__ X, const short* __restrict__ BigT,
        short* __restrict__ qb, short* __restrict__ kb, short* __restrict__ vtb) {
    int wave = threadIdx.x >> 6;
    int lane = threadIdx.x & 63;
    int lq = lane & 15, quad = lane >> 4;
    int tm = blockIdx.x * 128;
    int tn = blockIdx.y * 64;

    floatx4 acc[2][4];
    for (int a = 0; a < 2; ++a)
        for (int n = 0; n < 4; ++n)
            acc[a][n] = (floatx4){0.f, 0.f, 0.f, 0.f};

    const short* A0 = X + (tm + wave * 32 + lq) * 640 + quad * 8;
    const short* A1 = A0 + 16 * 640;
    const short* Bb = BigT + (tn + lq) * 640 + quad * 8;

    for (int k0 = 0; k0 < 640; k0 += 32) {
        short8 a0 = *(const short8*)(A0 + k0);
        short8 a1 = *(const short8*)(A1 + k0);
        short8 b0 = *(const short8*)(Bb + k0);
        short8 b1 = *(const short8*)(Bb + 16 * 640 + k0);
        short8 b2 = *(const short8*)(Bb + 32 * 640 + k0);
        short8 b3 = *(const short8*)(Bb + 48 * 640 + k0);
        acc[0][0] = __builtin_amdgcn_mfma_f32_16x16x32_bf16(a0, b0, acc[0][0], 0, 0, 0);
        acc[0][1] = __builtin_amdgcn_mfma_f32_16x16x32_bf16(a0, b1, acc[0][1], 0, 0, 0);
        acc[0][2] = __builtin_amdgcn_mfma_f32_16x16x32_bf16(a0, b2, acc[0][2], 0, 0, 0);
        acc[0][3] = __builtin_amdgcn_mfma_f32_16x16x32_bf16(a0, b3, acc[0][3], 0, 0, 0);
        acc[1][0] = __builtin_amdgcn_mfma_f32_16x16x32_bf16(a1, b0, acc[1][0], 0, 0, 0);
        acc[1][1] = __builtin_amdgcn_mfma_f32_16x16x32_bf16(a1, b1, acc[1][1], 0, 0, 0);
        acc[1][2] = __builtin_amdgcn_mfma_f32_16x16x32_bf16(a1, b2, acc[1][2], 0, 0, 0);
        acc[1][3] = __builtin_amdgcn_mfma_f32_16x16x32_bf16(a1, b3, acc[1][3], 0, 0, 0);
    }

    // whole 64-wide N-tile lies in one (w, h) since 640 = 10*64
    int w = tn / 640;
    int hh = (tn % 640) / 64;
    const float qscale = 0.18033688011112042f;  // (1/sqrt(64)) * log2(e)

    for (int af = 0; af < 2; ++af) {
        for (int nt = 0; nt < 4; ++nt) {
            int kd = nt * 16 + lq;
            for (int r = 0; r < 4; ++r) {
                int m = tm + wave * 32 + af * 16 + quad * 4 + r;
                int b = m >> 11, s = m & 2047;
                float val = acc[af][nt][r];
                if (w == 0) {
                    qb[((b * H_ + hh) * S_ + s) * KD_ + kd] = f2bf(val * qscale);
                } else if (w == 1) {
                    kb[((b * H_ + hh) * S_ + s) * KD_ + kd] = f2bf(val);
                } else {
                    vtb[((b * H_ + hh) * KD_ + kd) * S_ + s] = f2bf(val);
                }
            }
        }
    }
}

// ---------------------------------------------------------------------------
// Kernel 3: flash attention. One WG (4 waves) per (b, h, 64-row Q tile).
// Each wave owns 16 Q rows. Loop over 32 key-tiles of 64:
//   QK^T (8 mfma) -> online softmax (shuffle reduce over 16 lanes) ->
//   P via wave-private LDS (C-layout -> A-layout) -> PV (8 mfma).
// Scores arrive pre-scaled by 1/8*log2(e) (folded into q), so exp2 suffices.
// ---------------------------------------------------------------------------
__global__ __launch_bounds__(256) void attn(
        const short* __restrict__ qb, const short* __restrict__ kb,
        const short* __restrict__ vtb, short* __restrict__ zb) {
    // stride 72 shorts = 144 B: 2-way bank aliasing only (free) for both the
    // b16 writes and the b64 A-frag reads.
    __shared__ __align__(16) short Pbuf[4][16][72];

    int wave = threadIdx.x >> 6;
    int lane = threadIdx.x & 63;
    int lq = lane & 15, quad = lane >> 4;
    int b = blockIdx.z, h = blockIdx.y;
    int q0 = blockIdx.x * 64;

    const short* qp = qb + (b * H_ + h) * S_ * KD_;
    const short* kp = kb + (b * H_ + h) * S_ * KD_;
    const short* vp = vtb + (b * H_ + h) * KD_ * S_;

    short8 qf0, qf1;
    {
        int row = q0 + wave * 16 + lq;
        qf0 = *(const short8*)(qp + row * 64 + quad * 8);
        qf1 = *(const short8*)(qp + row * 64 + 32 + quad * 8);
    }

    floatx4 O[4];
    for (int n = 0; n < 4; ++n) O[n] = (floatx4){0.f, 0.f, 0.f, 0.f};
    float mrow[4] = {-INFINITY, -INFINITY, -INFINITY, -INFINITY};
    float lrow[4] = {0.f, 0.f, 0.f, 0.f};

    for (int t0 = 0; t0 < S_; t0 += 64) {
        // ---- QK^T ----
        floatx4 sf[4];
        for (int nt = 0; nt < 4; ++nt) {
            const short* kr = kp + (t0 + nt * 16 + lq) * 64 + quad * 8;
            short8 bk0 = *(const short8*)(kr);
            short8 bk1 = *(const short8*)(kr + 32);
            floatx4 z4 = (floatx4){0.f, 0.f, 0.f, 0.f};
            z4 = __builtin_amdgcn_mfma_f32_16x16x32_bf16(qf0, bk0, z4, 0, 0, 0);
            sf[nt] = __builtin_amdgcn_mfma_f32_16x16x32_bf16(qf1, bk1, z4, 0, 0, 0);
        }
        // ---- online softmax (rows = quad*4 + r, cols spread over 16 lanes) ----
        float alpha[4];
        for (int r = 0; r < 4; ++r) {
            float mx = fmaxf(fmaxf(sf[0][r], sf[1][r]), fmaxf(sf[2][r], sf[3][r]));
            mx = fmaxf(mx, __shfl_xor(mx, 1));
            mx = fmaxf(mx, __shfl_xor(mx, 2));
            mx = fmaxf(mx, __shfl_xor(mx, 4));
            mx = fmaxf(mx, __shfl_xor(mx, 8));
            float mnew = fmaxf(mrow[r], mx);
            alpha[r] = __builtin_amdgcn_exp2f(mrow[r] - mnew);  // exp2(-inf)=0 on first tile
            mrow[r] = mnew;
        }
        float rs[4] = {0.f, 0.f, 0.f, 0.f};
        for (int nt = 0; nt < 4; ++nt) {
            for (int r = 0; r < 4; ++r) {
                float p = __builtin_amdgcn_exp2f(sf[nt][r] - mrow[r]);
                sf[nt][r] = p;
                rs[r] += p;
            }
        }
        for (int r = 0; r < 4; ++r) {
            float s = rs[r];
            s += __shfl_xor(s, 1);
            s += __shfl_xor(s, 2);
            s += __shfl_xor(s, 4);
            s += __shfl_xor(s, 8);
            lrow[r] = lrow[r] * alpha[r] + s;
        }
        for (int nt = 0; nt < 4; ++nt)
            for (int r = 0; r < 4; ++r)
                O[nt][r] *= alpha[r];

        // ---- P: C-layout regs -> LDS row-major (wave-private) ----
        for (int nt = 0; nt < 4; ++nt)
            for (int r = 0; r < 4; ++r)
                Pbuf[wave][quad * 4 + r][nt * 16 + lq] = f2bf(sf[nt][r]);
        __syncthreads();

        // ---- PV ----
        for (int ks = 0; ks < 2; ++ks) {
            const short* prow = &Pbuf[wave][lq][ks * 32 + quad * 8];
            short4v pa = *(const short4v*)(prow);
            short4v pb = *(const short4v*)(prow + 4);
            short8 pf;
            pf[0] = pa[0]; pf[1] = pa[1]; pf[2] = pa[2]; pf[3] = pa[3];
            pf[4] = pb[0]; pf[5] = pb[1]; pf[6] = pb[2]; pf[7] = pb[3];
            for (int nt = 0; nt < 4; ++nt) {
                short8 bv = *(const short8*)(vp + (nt * 16 + lq) * S_ + t0 + ks * 32 + quad * 8);
                O[nt] = __builtin_amdgcn_mfma_f32_16x16x32_bf16(pf, bv, O[nt], 0, 0, 0);
            }
        }
        __syncthreads();
    }

    // ---- epilogue: z[b][s][h*64+kd] ----
    for (int nt = 0; nt < 4; ++nt) {
        for (int r = 0; r < 4; ++r) {
            int s = q0 + wave * 16 + quad * 4 + r;
            float o = O[nt][r] / lrow[r];
            zb[(b * S_ + s) * 640 + h * 64 + nt * 16 + lq] = f2bf(o);
        }
    }
}

// ---------------------------------------------------------------------------
// Kernel 4: output projection.  out(8192x640) = Z(8192x640) @ WoT^T.
// Same structure as qkv_gemm; fp32 row-major store to d_out.
// ---------------------------------------------------------------------------
__global__ __launch_bounds__(256) void out_gemm(
        const short* __restrict__ Z, const short* __restrict__ WoT,
        float* __restrict__ out) {
    int wave = threadIdx.x >> 6;
    int lane = threadIdx.x & 63;
    int lq = lane & 15, quad = lane >> 4;
    int tm = blockIdx.x * 128;
    int tn = blockIdx.y * 64;

    floatx4 acc[2][4];
    for (int a = 0; a < 2; ++a)
        for (int n = 0; n < 4; ++n)
            acc[a][n] = (floatx4){0.f, 0.f, 0.f, 0.f};

    const short* A0 = Z + (tm + wave * 32 + lq) * 640 + quad * 8;
    const short* A1 = A0 + 16 * 640;
    const short* Bb = WoT + (tn + lq) * 640 + quad * 8;

    for (int k0 = 0; k0 < 640; k0 += 32) {
        short8 a0 = *(const short8*)(A0 + k0);
        short8 a1 = *(const short8*)(A1 + k0);
        short8 b0 = *(const short8*)(Bb + k0);
        short8 b1 = *(const short8*)(Bb + 16 * 640 + k0);
        short8 b2 = *(const short8*)(Bb + 32 * 640 + k0);
        short8 b3 = *(const short8*)(Bb + 48 * 640 + k0);
        acc[0][0] = __builtin_amdgcn_mfma_f32_16x16x32_bf16(a0, b0, acc[0][0], 0, 0, 0);
        acc[0][1] = __builtin_amdgcn_mfma_f32_16x16x32_bf16(a0, b1, acc[0][1], 0, 0, 0);
        acc[0][2] = __builtin_amdgcn_mfma_f32_16x16x32_bf16(a0, b2, acc[0][2], 0, 0, 0);
        acc[0][3] = __builtin_amdgcn_mfma_f32_16x16x32_bf16(a0, b3, acc[0][3], 0, 0, 0);
        acc[1][0] = __builtin_amdgcn_mfma_f32_16x16x32_bf16(a1, b0, acc[1][0], 0, 0, 0);
        acc[1][1] = __builtin_amdgcn_mfma_f32_16x16x32_bf16(a1, b1, acc[1][1], 0, 0, 0);
        acc[1][2] = __builtin_amdgcn_mfma_f32_16x16x32_bf16(a1, b2, acc[1][2], 0, 0, 0);
        acc[1][3] = __builtin_amdgcn_mfma_f32_16x16x32_bf16(a1, b3, acc[1][3], 0, 0, 0);
    }

    for (int af = 0; af < 2; ++af) {
        for (int nt = 0; nt < 4; ++nt) {
            for (int r = 0; r < 4; ++r) {
                int m = tm + wave * 32 + af * 16 + quad * 4 + r;
                out[m * 640 + tn + nt * 16 + lq] = acc[af][nt][r];
            }
        }
    }
}

// ---------------------------------------------------------------------------
extern "C" void kernel_launch(void* const* d_in, const int* in_sizes, int n_in,
                              void* d_out, int out_size, void* d_ws, size_t ws_size,
                              hipStream_t stream) {
    const float* x  = (const float*)d_in[0];
    const float* Wq = (const float*)d_in[1];
    const float* Wk = (const float*)d_in[2];
    const float* Wv = (const float*)d_in[3];
    const float* Wo = (const float*)d_in[4];
    float* out = (float*)d_out;

    char* ws = (char*)d_ws;
    // workspace layout (bytes):
    short* BigT = (short*)(ws);                    //  1920*640*2 = 2,457,600
    short* WoT  = (short*)(ws + 2457600);          //   640*640*2 =   819,200
    short* xb   = (short*)(ws + 3276800);          // 8192*640*2  = 10,485,760
    short* qb   = (short*)(ws + 13762560);         // 4*10*2048*64*2 = 10,485,760
    short* kb   = (short*)(ws + 24248320);
    short* vtb  = (short*)(ws + 34734080);
    short* zb   = (short*)(ws + 45219840);         // end = 55,705,600 B

    pack_x<<<dim3(5120), dim3(256), 0, stream>>>(x, xb);
    transpose_weights<<<dim3(6400), dim3(256), 0, stream>>>(Wq, Wk, Wv, Wo, BigT, WoT);
    qkv_gemm<<<dim3(64, 30), dim3(256), 0, stream>>>(xb, BigT, qb, kb, vtb);
    attn<<<dim3(32, H_, B_), dim3(256), 0, stream>>>(qb, kb, vtb, zb);
    out_gemm<<<dim3(64, 10), dim3(256), 0, stream>>>(zb, WoT, out);
}